// Round 6
// baseline (133.406 us; speedup 1.0000x reference)
//
#include <hip/hip_runtime.h>

// Problem constants (match reference)
#define VOCABN 100
#define EMBEDN 16
#define STATEN 7
#define OUTN   10
#define BATCHN 4096
#define SEQT   512
#define L2E 1.44269504088896340736f

typedef float v2f __attribute__((ext_vector_type(2)));

// v_exp_f32 / v_rcp_f32 saturate correctly at inf/0 -> gate forms below are
// exact at the extremes.
__device__ __forceinline__ float fexp2(float x){ float r; asm("v_exp_f32 %0, %1":"=v"(r):"v"(x)); return r; }
__device__ __forceinline__ float frcp (float x){ float r; asm("v_rcp_f32 %0, %1":"=v"(r):"v"(x)); return r; }

// DPP helpers. row_ror:n = 0x120+n (16-lane ring); quad_perm [1,0,3,2] = 0xB1.
template<int C> __device__ __forceinline__ int dppi(int x){
  return __builtin_amdgcn_update_dpp(0, x, C, 0xF, 0xF, true);
}
template<int C> __device__ __forceinline__ float dppf(float x){
  return __int_as_float(__builtin_amdgcn_update_dpp(0, __float_as_int(x), C, 0xF, 0xF, true));
}

// ---------------------------------------------------------------------------
// Kernel A: embW2[v][pos] = pre-scaled gate pre-activations, pos = s*2+p.
// p0 -> gates (i,f), p1 -> gates (g,o). Scales: i,f,o: -log2e; g: +2log2e.
// Pad state s=7 (pos 14,15) -> zeros.
// ---------------------------------------------------------------------------
__global__ void embw_kernel(const float* __restrict__ emb, const float* __restrict__ W,
                            const float* __restrict__ b, float* __restrict__ embw){
  int v = blockIdx.x, j = threadIdx.x;          // j 0..31
  int pos = j >> 1, g2 = j & 1;
  int s = pos >> 1, p = pos & 1, gate = p*2 + g2;
  float val = 0.0f;
  if (s < STATEN) {
    int col = gate*STATEN + s;
    val = b[col];
    #pragma unroll
    for (int e = 0; e < EMBEDN; ++e) val = fmaf(emb[v*EMBEDN+e], W[e*28+col], val);
    val *= (gate == 2) ? (2.0f*L2E) : (-L2E);
  }
  embw[v*32 + pos*2 + g2] = val;
}

// ---------------------------------------------------------------------------
// Kernel B: TLP-first layout. 2048 single-wave blocks; each wave carries TWO
// chains (groups 0,1 of 16 lanes; groups 2,3 duplicate the compute and skip
// stores — lanes are free, waves are not). 2 waves/SIMD hardware-interleave,
// filling each other's transcendental-latency and DPP-hazard stalls; no
// inter-wave sync anywhere. Lane (s=pos>>1, p=pos&1) computes packed gate
// cols (i,f)[p0] / (g,o)[p1]; depth-1 row_ror DPP h-broadcast; weights
// pre-permuted by discovered sigma, pre-scaled (C tracked in 2*log2e*c).
// Dense+softmax: round-3's branch-free staged flush across the 8 steps of
// the following octet (lane s = timestep s of the octet, cols p*5..p*5+4).
// ---------------------------------------------------------------------------
__global__ void __launch_bounds__(64)
lstm_kernel(const int* __restrict__ tokens, const float* __restrict__ embw,
            const float* __restrict__ U, const float* __restrict__ Wd,
            const float* __restrict__ bdv, float* __restrict__ out){
  __shared__ float embW_s[VOCABN*32];   // 12.8 KB
  __shared__ int   tok_s[2*520];        // 2 chains (+pads for over-read)

  const int tid = threadIdx.x;
  const int b0 = blockIdx.x*2;

  for (int i=tid;i<VOCABN*8;i+=64) ((float4*)embW_s)[i]=((const float4*)embw)[i];
  for (int i=tid;i<2*128;i+=64){ int r=i>>7,c4=i&127;
    int4 v=((const int4*)(tokens+(size_t)(b0+r)*SEQT))[c4];
    *((int4*)&tok_s[r*520+c4*4])=v; }
  if (tid<2){ tok_s[tid*520+512]=0; tok_s[tid*520+513]=0; tok_s[tid*520+514]=0; }
  __syncthreads();

  const int pos=tid&15, g=tid>>4, s=pos>>1, p=pos&1;
  const int ch=g&1;               // chain within block (groups 2,3 duplicate)
  const bool act=(g<2);           // only groups 0,1 store

  // sigma discovery: run own state id through the exact broadcast net
  int sg[8];
  sg[0]=s;
  sg[1]=dppi<0x122>(s); sg[2]=dppi<0x124>(s); sg[3]=dppi<0x126>(s);
  sg[4]=dppi<0x128>(s); sg[5]=dppi<0x12A>(s); sg[6]=dppi<0x12C>(s); sg[7]=dppi<0x12E>(s);

  // recurrent weights: packed {colA,colB}, pre-permuted, pre-scaled
  v2f Ucp[8];
  {
    const int gA=p*2, gB=p*2+1;
    const float sA = (gA==2)?(2.0f*L2E):(-L2E);
    const float sB = (gB==2)?(2.0f*L2E):(-L2E);
    #pragma unroll
    for (int k=0;k<8;++k){
      int sk=sg[k]; bool vld=(sk<STATEN)&&(s<STATEN);
      Ucp[k].x = vld ? U[sk*28+gA*7+s]*sA : 0.0f;
      Ucp[k].y = vld ? U[sk*28+gB*7+s]*sB : 0.0f;
    }
  }
  // dense weights (half per parity), pre-permuted by sigma, pre-scaled L2E
  float Wdc[8][5], bdr[5];
  #pragma unroll
  for (int k=0;k<8;++k){ int sk=sg[k];
    #pragma unroll
    for (int o=0;o<5;++o) Wdc[k][o] = (sk<STATEN)? Wd[sk*10+p*5+o]*L2E : 0.0f; }
  #pragma unroll
  for (int o=0;o<5;++o) bdr[o]=bdv[p*5+o]*L2E;

  const int* trow=&tok_s[ch*520];
  float* outp = out + ((size_t)(b0+ch)*SEQT + s)*OUTN + p*5;

  float hh[8], hc[8], lg[5], ee[5];
  #pragma unroll
  for (int k=0;k<8;++k){ hh[k]=0.0f; hc[k]=0.0f; }
  #pragma unroll
  for (int o=0;o<5;++o){ lg[o]=0.0f; ee[o]=0.0f; }
  float mx=0.0f, rs=0.0f;

  // prefetch queues: embW depth-2, token depth-3
  int tk2 = trow[2];
  v2f pf0 = *(const v2f*)&embW_s[trow[0]*32+pos*2];
  v2f pf1 = *(const v2f*)&embW_s[trow[1]*32+pos*2];
  float Cc=0.0f, h=0.0f;

  for (int t8=0;t8<SEQT;t8+=8){
    #pragma unroll
    for (int u=0;u<8;++u){
      // prefetches (consumed 2 / 1 iterations later)
      v2f pf2 = *(const v2f*)&embW_s[tk2*32+pos*2];
      int tk3 = trow[t8+u+3];

      // broadcast h_{t-1} across the 16-lane chain (depth-1 DPP net)
      float r0=h;
      float r1=dppf<0x122>(h), r2=dppf<0x124>(h), r3=dppf<0x126>(h);
      float r4=dppf<0x128>(h), r5=dppf<0x12A>(h), r6=dppf<0x12C>(h), r7=dppf<0x12E>(h);

      // lane-pair of state s captures h-vector of timestep t-1 when u==s+1 (mod 8)
      bool cap = (s==((u+7)&7));
      hh[0]=cap?r0:hh[0]; hh[1]=cap?r1:hh[1]; hh[2]=cap?r2:hh[2]; hh[3]=cap?r3:hh[3];
      hh[4]=cap?r4:hh[4]; hh[5]=cap?r5:hh[5]; hh[6]=cap?r6:hh[6]; hh[7]=cap?r7:hh[7];

      // ---- branch-free staged flush of the PREVIOUS octet ----
      if (u==0){ hc[0]=hh[0];hc[1]=hh[1];hc[2]=hh[2];hc[3]=hh[3];
                 hc[4]=hh[4];hc[5]=hh[5];hc[6]=hh[6];hc[7]=hh[7]; }
      if (u==1){
        float a0=bdr[0], a1=bdr[1];
        #pragma unroll
        for (int k=0;k<8;++k){ a0=__builtin_fmaf(hc[k],Wdc[k][0],a0);
                               a1=__builtin_fmaf(hc[k],Wdc[k][1],a1); }
        lg[0]=a0; lg[1]=a1; }
      if (u==2){
        float a2=bdr[2], a3=bdr[3];
        #pragma unroll
        for (int k=0;k<8;++k){ a2=__builtin_fmaf(hc[k],Wdc[k][2],a2);
                               a3=__builtin_fmaf(hc[k],Wdc[k][3],a3); }
        lg[2]=a2; lg[3]=a3; }
      if (u==3){
        float a4=bdr[4];
        #pragma unroll
        for (int k=0;k<8;++k) a4=__builtin_fmaf(hc[k],Wdc[k][4],a4);
        lg[4]=a4; }
      if (u==4){
        float m=fmaxf(fmaxf(fmaxf(lg[0],lg[1]),fmaxf(lg[2],lg[3])),lg[4]);
        mx=fmaxf(m, dppf<0xB1>(m)); }              // combine with parity partner
      if (u==5){
        ee[0]=fexp2(lg[0]-mx); ee[1]=fexp2(lg[1]-mx); ee[2]=fexp2(lg[2]-mx);
        ee[3]=fexp2(lg[3]-mx); ee[4]=fexp2(lg[4]-mx); }
      if (u==6){
        float sm=((ee[0]+ee[1])+(ee[2]+ee[3]))+ee[4];
        rs=frcp(sm + dppf<0xB1>(sm)); }
      if (u==7){
        if (t8>0 && act){
          outp[0]=ee[0]*rs; outp[1]=ee[1]*rs; outp[2]=ee[2]*rs;
          outp[3]=ee[3]*rs; outp[4]=ee[4]*rs;
        }
        if (t8>0) outp += 8*OUTN;
      }

      // ---- z = embW'[tok] + h @ U' (packed v_pk_fma_f32, tree) ----
      v2f z01=__builtin_elementwise_fma((v2f){r1,r1},Ucp[1],
              __builtin_elementwise_fma((v2f){r0,r0},Ucp[0],pf0));
      v2f z23=__builtin_elementwise_fma((v2f){r3,r3},Ucp[3],(v2f){r2,r2}*Ucp[2]);
      v2f z45=__builtin_elementwise_fma((v2f){r5,r5},Ucp[5],(v2f){r4,r4}*Ucp[4]);
      v2f z67=__builtin_elementwise_fma((v2f){r7,r7},Ucp[7],(v2f){r6,r6}*Ucp[6]);
      v2f zv=(z01+z23)+(z45+z67);

      // gates: p0: gA=i, gB=f ; p1: gA=rcp-part of g, gB=o
      float gA=frcp(1.0f+fexp2(zv.x));
      float gB=frcp(1.0f+fexp2(zv.y));
      float gg_s=__builtin_fmaf(gA,-4.0f*L2E,2.0f*L2E); // 2L2E*tanh(zg) on p1
      float gg_x=dppf<0xB1>(gg_s);                      // p0 <- p1
      float go_x=dppf<0xB1>(gB);                        // p0 <- p1's o
      Cc=__builtin_fmaf(gB,Cc,gA*gg_x);                 // valid on p0 (2L2E*c)
      float rcpC=frcp(1.0f+fexp2(Cc));                  // valid on p0
      float rcpC_x=dppf<0xB1>(rcpC);                    // p1 <- p0
      float go_u = p ? gB     : go_x;
      float rc_u = p ? rcpC_x : rcpC;
      h=__builtin_fmaf(-2.0f*go_u, rc_u, go_u);         // h = o*tanh(c)

      pf0=pf1; pf1=pf2; tk2=tk3;
    }
  }

  // ---- epilogue: capture h_511 (slot 7), flush final octet (ts 504..511) ----
  {
    float r0=h;
    float r1=dppf<0x122>(h), r2=dppf<0x124>(h), r3=dppf<0x126>(h);
    float r4=dppf<0x128>(h), r5=dppf<0x12A>(h), r6=dppf<0x12C>(h), r7=dppf<0x12E>(h);
    bool cap = (s==7);
    hh[0]=cap?r0:hh[0]; hh[1]=cap?r1:hh[1]; hh[2]=cap?r2:hh[2]; hh[3]=cap?r3:hh[3];
    hh[4]=cap?r4:hh[4]; hh[5]=cap?r5:hh[5]; hh[6]=cap?r6:hh[6]; hh[7]=cap?r7:hh[7];
    float a[5];
    #pragma unroll
    for (int o=0;o<5;++o){ a[o]=bdr[o];
      #pragma unroll
      for (int k=0;k<8;++k) a[o]=__builtin_fmaf(hh[k],Wdc[k][o],a[o]); }
    float m=fmaxf(fmaxf(fmaxf(a[0],a[1]),fmaxf(a[2],a[3])),a[4]);
    m=fmaxf(m, dppf<0xB1>(m));
    float e0=fexp2(a[0]-m), e1=fexp2(a[1]-m), e2=fexp2(a[2]-m),
          e3=fexp2(a[3]-m), e4=fexp2(a[4]-m);
    float sm=((e0+e1)+(e2+e3))+e4;
    float r=frcp(sm + dppf<0xB1>(sm));
    if (act){
      outp[0]=e0*r; outp[1]=e1*r; outp[2]=e2*r; outp[3]=e3*r; outp[4]=e4*r;
    }
  }
}

// ---------------------------------------------------------------------------
// inputs: 0 tokens 1 emb 2 W 3 U 4 b 5 Wd 6 bd ; out f32 B*T*10.
// d_ws: 12800 B for the pre-scaled embW table (rewritten every call).
// ---------------------------------------------------------------------------
extern "C" void kernel_launch(void* const* d_in, const int* in_sizes, int n_in,
                              void* d_out, int out_size, void* d_ws, size_t ws_size,
                              hipStream_t stream) {
  const int*   tokens = (const int*)d_in[0];
  const float* emb    = (const float*)d_in[1];
  const float* W      = (const float*)d_in[2];
  const float* U      = (const float*)d_in[3];
  const float* b      = (const float*)d_in[4];
  const float* Wd     = (const float*)d_in[5];
  const float* bd     = (const float*)d_in[6];
  float* outp = (float*)d_out;
  float* embw = (float*)d_ws;

  embw_kernel<<<dim3(VOCABN), dim3(32), 0, stream>>>(emb, W, b, embw);
  lstm_kernel<<<dim3(BATCHN/2), dim3(64), 0, stream>>>(tokens, embw, U, Wd, bd, outp);
}